// Round 7
// baseline (530.561 us; speedup 1.0000x reference)
//
#include <hip/hip_runtime.h>
#include <math.h>

typedef __attribute__((ext_vector_type(8))) short short8;
typedef __attribute__((ext_vector_type(4))) float floatx4;

__device__ inline float bf2f(short s) {
    union { unsigned u; float f; } x; x.u = ((unsigned)(unsigned short)s) << 16; return x.f;
}
__device__ inline short f2bf(float f) {
    union { float f; unsigned u; } x; x.f = f;
    unsigned r = x.u + 0x7fff + ((x.u >> 16) & 1);
    return (short)(r >> 16);
}

struct WSet {
    const float *fw1, *fb1, *fw2, *sw1, *sb1, *sw2, *sb2, *dw1, *db1, *dw2, *db2;
};

// ---------------- weight prep (both scales, blockIdx.y = scale) ----------------
__global__ __launch_bounds__(256) void wprep(WSet a0, WSet a1,
    short* __restrict__ W1f, short* __restrict__ W2af, short* __restrict__ W2bf,
    float* __restrict__ B1p, float* __restrict__ B2bp)
{
    const int s = blockIdx.y;
    const WSet A = s ? a1 : a0;
    W1f  += (size_t)s * 491520;
    W2af += (size_t)s * 65536;
    W2bf += (size_t)s * 98304;
    B1p  += s * 1280;
    B2bp += s * 128;
    int id = blockIdx.x * 256 + threadIdx.x;
    if (id < 491520) {
        int e = id & 7, l = (id >> 3) & 63, g = (id >> 9) & 15, rest = id >> 13;
        int kc = rest % 12, c = rest / 12;
        int m = c * 256 + g * 16 + (l & 15);
        int k = kc * 32 + (l >> 4) * 8 + e;
        float v = 0.f;
        if (m < 512) v = A.fw1[m * 384 + k];
        else if (m < 1024) v = A.sw1[(m - 512) * 384 + k];
        else if (m < 1152) v = A.dw1[(m - 1024) * 384 + k];
        W1f[id] = f2bf(v);
        return;
    }
    id -= 491520;
    if (id < 65536) {
        int e = id & 7, l = (id >> 3) & 63, g = (id >> 9) & 7, ka = id >> 12;
        int r = g * 16 + (l & 15), k = ka * 32 + (l >> 4) * 8 + e;
        W2af[id] = f2bf(A.fw2[r * 512 + k]);
        return;
    }
    id -= 65536;
    if (id < 98304) {
        int e = id & 7, l = (id >> 3) & 63, g = (id >> 9) & 7, kb = id >> 12;
        int r = g * 16 + (l & 15), krel = kb * 32 + (l >> 4) * 8 + e;
        float v = 0.f;
        if (r < 64 && krel < 512) v = A.sw2[r * 512 + krel];
        else if (r == 64 && krel >= 512 && krel < 640) v = A.dw2[krel - 512];
        W2bf[id] = f2bf(v);
        return;
    }
    id -= 98304;
    if (id < 1280) {
        float v = 0.f;
        if (id < 512) v = A.fb1[id];
        else if (id < 1024) v = A.sb1[id - 512];
        else if (id < 1152) v = A.db1[id - 1024];
        B1p[id] = v;
        return;
    }
    id -= 1280;
    if (id < 128) B2bp[id] = id < 64 ? A.sb2[id] : id == 64 ? A.db2[0] : 0.f;
}

// ---------------- fused MLP v4: x (fp32) -> staged tile -> h (LDS) -> feat + E + pu ----------------
// grid x: 0..63 = s0 tiles, 64..79 = s1 (pooled) tiles. blockIdx.y = batch.
__global__ __launch_bounds__(256, 2) void fused_mlp(
    const short* __restrict__ W1f_, const float* __restrict__ B1p_,
    const short* __restrict__ W2af_, const float* __restrict__ fb2_0, const float* __restrict__ fb2_1,
    const short* __restrict__ W2bf_, const float* __restrict__ B2bp_,
    const float* __restrict__ x,
    float* __restrict__ feat0, float* __restrict__ feat1,
    short* __restrict__ Eg0, short* __restrict__ Eg1,
    float* __restrict__ pu0, float* __restrict__ pu1)
{
    __shared__ short xs[12 * 2048];   // 48 KB fragment-order x tile
    __shared__ short hs[8 * 2048];    // 32 KB h chunk (also staging scratch)
    const int tid = threadIdx.x;
    const int wid = tid >> 6, lane = tid & 63;
    const int l15 = lane & 15, q = lane >> 4;
    const int bx = blockIdx.x, b = blockIdx.y;
    const int sc = bx >= 64;
    const int tile = sc ? bx - 64 : bx;
    const int N = sc ? 1024 : 4096;
    const int n0 = tile * 64;
    const short* W1f = W1f_ + (size_t)sc * 491520;
    const float* B1p = B1p_ + sc * 1280;
    const short* W2af = W2af_ + (size_t)sc * 65536;
    const short* W2bf = W2bf_ + (size_t)sc * 98304;
    const float* fb2 = sc ? fb2_1 : fb2_0;
    const float* B2bp = B2bp_ + sc * 128;
    float* feat = (sc ? feat1 : feat0) + (long)b * 128 * N;
    short* Eg = (sc ? Eg1 : Eg0) + (long)b * 65 * N;
    float* pu = sc ? pu1 : pu0;
    const int npart = sc ? 16 : 64;

    // ---- stage x tile [64 n x 384 c] from fp32 x via scr bounce ----
    {
        short* scr = hs;                               // [192][72] bf16 per round
        const float* xb = x + (long)b * 384 * 4096;
        for (int r = 0; r < 2; r++) {
            if (sc == 0) {
                #pragma unroll
                for (int it = 0; it < 3; it++) {
                    int cl = it * 64 + (tid >> 2);
                    const float* src = xb + (long)(r * 192 + cl) * 4096 + n0 + (tid & 3) * 16;
                    short tmp[16];
                    #pragma unroll
                    for (int v = 0; v < 4; v++) {
                        float4 f4 = *(const float4*)(src + v * 4);
                        tmp[v*4+0] = f2bf(f4.x); tmp[v*4+1] = f2bf(f4.y);
                        tmp[v*4+2] = f2bf(f4.z); tmp[v*4+3] = f2bf(f4.w);
                    }
                    *(short8*)(scr + cl * 72 + (tid & 3) * 16) = *(short8*)tmp;
                    *(short8*)(scr + cl * 72 + (tid & 3) * 16 + 8) = *(short8*)(tmp + 8);
                }
            } else {
                #pragma unroll
                for (int it = 0; it < 3; it++) {
                    int cl = it * 64 + (tid >> 2);
                    int h4 = tid & 3, pr = h4 >> 1, ch = h4 & 1;
                    const float* srcA = xb + (long)(r * 192 + cl) * 4096
                                      + (tile * 4 + pr * 2) * 64 + ch * 32;
                    const float* srcB = srcA + 64;
                    short tmp[16];
                    #pragma unroll
                    for (int v = 0; v < 16; v++) {
                        float s4 = srcA[2*v] + srcA[2*v+1] + srcB[2*v] + srcB[2*v+1];
                        tmp[v] = f2bf(0.25f * s4);
                    }
                    *(short8*)(scr + cl * 72 + pr * 32 + ch * 16) = *(short8*)tmp;
                    *(short8*)(scr + cl * 72 + pr * 32 + ch * 16 + 8) = *(short8*)(tmp + 8);
                }
            }
            __syncthreads();
            #pragma unroll
            for (int u = 0; u < 6; u++) {
                int idx = tid * 6 + u;
                int n = idx & 63, c8l = idx >> 6;       // c8l 0..23
                short tmp[8];
                #pragma unroll
                for (int e = 0; e < 8; e++) tmp[e] = scr[(c8l * 8 + e) * 72 + n];
                int cg = r * 192 + c8l * 8;
                int kc = cg >> 5, qq = (cg >> 3) & 3;
                *(short8*)(xs + kc * 2048 + (n >> 4) * 512 + ((qq << 4) | (n & 15)) * 8) = *(short8*)tmp;
            }
            __syncthreads();
        }
    }

    floatx4 acc2[4][4];
    #pragma unroll
    for (int i = 0; i < 4; i++)
        #pragma unroll
        for (int j = 0; j < 4; j++) acc2[i][j] = floatx4{0.f, 0.f, 0.f, 0.f};

    auto phase2 = [&](int pc) {
        if (pc < 2) {
            for (int kc2 = 0; kc2 < 8; kc2++) {
                short8 bfr[4];
                #pragma unroll
                for (int j = 0; j < 4; j++)
                    bfr[j] = *(short8*)(hs + kc2 * 2048 + j * 512 + lane * 8);
                short8 aA = *(const short8*)(W2af + ((pc * 8 + kc2) * 8 + 2 * wid) * 512 + lane * 8);
                short8 aB = *(const short8*)(W2af + ((pc * 8 + kc2) * 8 + 2 * wid + 1) * 512 + lane * 8);
                #pragma unroll
                for (int j = 0; j < 4; j++) {
                    acc2[0][j] = __builtin_amdgcn_mfma_f32_16x16x32_bf16(aA, bfr[j], acc2[0][j], 0, 0, 0);
                    acc2[1][j] = __builtin_amdgcn_mfma_f32_16x16x32_bf16(aB, bfr[j], acc2[1][j], 0, 0, 0);
                }
            }
        } else {
            for (int kc2 = 0; kc2 < 8; kc2++) {
                short8 bfr[4];
                #pragma unroll
                for (int j = 0; j < 4; j++)
                    bfr[j] = *(short8*)(hs + kc2 * 2048 + j * 512 + lane * 8);
                short8 aC = *(const short8*)(W2bf + (((pc - 2) * 8 + kc2) * 8 + wid) * 512 + lane * 8);
                #pragma unroll
                for (int j = 0; j < 4; j++)
                    acc2[2][j] = __builtin_amdgcn_mfma_f32_16x16x32_bf16(aC, bfr[j], acc2[2][j], 0, 0, 0);
                if (wid == 0) {
                    short8 aD = *(const short8*)(W2bf + (((pc - 2) * 8 + kc2) * 8 + 4) * 512 + lane * 8);
                    #pragma unroll
                    for (int j = 0; j < 4; j++)
                        acc2[3][j] = __builtin_amdgcn_mfma_f32_16x16x32_bf16(aD, bfr[j], acc2[3][j], 0, 0, 0);
                }
            }
        }
    };

    for (int c = 0; c < 5; c++) {
        floatx4 acc1[4][4];
        #pragma unroll
        for (int i = 0; i < 4; i++)
            #pragma unroll
            for (int j = 0; j < 4; j++) acc1[i][j] = floatx4{0.f, 0.f, 0.f, 0.f};
        const short* Wb = W1f + (long)c * 98304;
        short8 an[4];
        #pragma unroll
        for (int i = 0; i < 4; i++)
            an[i] = *(const short8*)(Wb + (wid * 4 + i) * 512 + lane * 8);
        for (int kc = 0; kc < 12; kc++) {
            short8 ac[4];
            #pragma unroll
            for (int i = 0; i < 4; i++) ac[i] = an[i];
            if (kc < 11) {
                #pragma unroll
                for (int i = 0; i < 4; i++)
                    an[i] = *(const short8*)(Wb + ((kc + 1) * 16 + wid * 4 + i) * 512 + lane * 8);
            }
            short8 bfr[4];
            #pragma unroll
            for (int j = 0; j < 4; j++)
                bfr[j] = *(short8*)(xs + kc * 2048 + j * 512 + lane * 8);
            #pragma unroll
            for (int i = 0; i < 4; i++)
                #pragma unroll
                for (int j = 0; j < 4; j++)
                    acc1[i][j] = __builtin_amdgcn_mfma_f32_16x16x32_bf16(ac[i], bfr[j], acc1[i][j], 0, 0, 0);
        }
        if (c > 0) phase2(c - 1);
        __syncthreads();   // hs readers done
        #pragma unroll
        for (int i = 0; i < 4; i++) {
            const int kc2 = wid * 2 + (i >> 1);
            const int qf = (i & 1) * 2 + (q >> 1);
            const int e0 = 4 * (q & 1);
            const int mrow = c * 256 + wid * 64 + i * 16 + q * 4;
            float bw[4];
            #pragma unroll
            for (int rr = 0; rr < 4; rr++) bw[rr] = B1p[mrow + rr];
            #pragma unroll
            for (int j = 0; j < 4; j++) {
                short pk[4];
                #pragma unroll
                for (int rr = 0; rr < 4; rr++)
                    pk[rr] = f2bf(fmaxf(acc1[i][j][rr] + bw[rr], 0.f));
                *(unsigned long long*)(hs + kc2 * 2048 + j * 512 + ((qf << 4) | l15) * 8 + e0) =
                    *(unsigned long long*)pk;
            }
        }
        __syncthreads();   // hs visible
    }
    phase2(4);

    // epilogue: feat (slots 0,1 of every wave)
    #pragma unroll
    for (int slot = 0; slot < 2; slot++) {
        int row0 = (2 * wid + slot) * 16 + q * 4;
        #pragma unroll
        for (int rr = 0; rr < 4; rr++) {
            float bv = fb2[row0 + rr];
            #pragma unroll
            for (int j = 0; j < 4; j++)
                feat[(long)(row0 + rr) * N + n0 + 16 * j + l15] = acc2[slot][j][rr] + bv;
        }
    }
    __syncthreads();               // phase2(4) hs reads done; reuse hs
    float* puld = (float*)hs;
    #pragma unroll
    for (int rr = 0; rr < 4; rr++) {
        int row = wid * 16 + q * 4 + rr;
        float bv = B2bp[row];
        float s = 0.f;
        #pragma unroll
        for (int j = 0; j < 4; j++) {
            float e = expf(acc2[2][j][rr] + bv);
            Eg[(long)row * N + n0 + 16 * j + l15] = f2bf(e);
            s += e;
        }
        s += __shfl_xor(s, 1); s += __shfl_xor(s, 2);
        s += __shfl_xor(s, 4); s += __shfl_xor(s, 8);
        if (l15 == 0) puld[row] = s;
    }
    if (wid == 0) {
        #pragma unroll
        for (int rr = 0; rr < 4; rr++) {
            int row = 64 + q * 4 + rr;
            bool valid = (row == 64);
            float bv = B2bp[64];
            float s = 0.f;
            #pragma unroll
            for (int j = 0; j < 4; j++) {
                float e = expf(acc2[3][j][rr] + bv);
                if (valid) {
                    Eg[(long)64 * N + n0 + 16 * j + l15] = f2bf(e);
                    s += e;
                }
            }
            s += __shfl_xor(s, 1); s += __shfl_xor(s, 2);
            s += __shfl_xor(s, 4); s += __shfl_xor(s, 8);
            if (valid && l15 == 0) puld[64] = s;
        }
    }
    __syncthreads();
    if (tid < 65)
        pu[((long)b * npart + tile) * 65 + tid] = puld[tid];
}

// ---------------- sk_step: 128-col chunks, 128 threads ----------------
// grid x: 0..31 = s0 chunks, 32..39 = s1. nout fixed 32/8.
__global__ __launch_bounds__(128) void sk_step(
    const short* __restrict__ Eg0, const short* __restrict__ Eg1,
    const float* __restrict__ pin0, const float* __restrict__ pin1,
    float* __restrict__ pout0, float* __restrict__ pout1, int nin0, int nin1)
{
    __shared__ short Es[65 * 136];
    __shared__ float evs[128];
    __shared__ float eus[65];
    const int t = threadIdx.x;
    const int bx = blockIdx.x, b = blockIdx.y;
    const int sc = bx >= 32;
    const int chunk = sc ? bx - 32 : bx;
    const int N = sc ? 1024 : 4096;
    const float invN = sc ? (1.0f / 1024.0f) : (1.0f / 4096.0f);
    const int n0 = chunk * 128;
    const short* Eb = (sc ? Eg1 : Eg0) + (long)b * 65 * N;
    const float* pin = sc ? pin1 : pin0;
    const int nin = sc ? nin1 : nin0;
    float* pout = sc ? pout1 : pout0;
    const int nout = sc ? 8 : 32;
    if (t < 65) {
        float s = 0.f;
        for (int ch = 0; ch < nin; ch++) s += pin[((long)b * nin + ch) * 65 + t];
        eus[t] = (1.0f / 65.0f) / s;
    }
    for (int it = t; it < 1040; it += 128) {
        int k = it >> 4, n8 = it & 15;
        *(short8*)(Es + k * 136 + n8 * 8) = *(const short8*)(Eb + (long)k * N + n0 + n8 * 8);
    }
    __syncthreads();
    float sv = 0.f;
    #pragma unroll 5
    for (int k = 0; k < 65; k++) sv += bf2f(Es[k * 136 + t]) * eus[k];
    evs[t] = invN / sv;
    __syncthreads();
    const int wid = t >> 6, lane = t & 63;
    for (int k = wid; k < 65; k += 2) {
        const short* er = Es + k * 136 + lane * 2;
        float s = bf2f(er[0]) * evs[lane * 2] + bf2f(er[1]) * evs[lane * 2 + 1];
        #pragma unroll
        for (int off = 32; off >= 1; off >>= 1) s += __shfl_xor(s, off);
        if (lane == 0) pout[((long)b * nout + chunk) * 65 + k] = s;
    }
}

// ---------------- sk_desc: 128-col chunks; final v-step; P; desc partials ----------------
__global__ __launch_bounds__(256) void sk_desc(
    const short* __restrict__ Eg0, const short* __restrict__ Eg1,
    const float* __restrict__ pin0, const float* __restrict__ pin1,
    const float* __restrict__ feat0, const float* __restrict__ feat1,
    float* __restrict__ part0, float* __restrict__ part1, int nin0, int nin1)
{
    __shared__ short Es[65 * 136];
    __shared__ float fs[128 * 33];
    __shared__ float evs[128];
    __shared__ float eus[65];
    const int t = threadIdx.x;
    const int bx = blockIdx.x, b = blockIdx.y;
    const int sc = bx >= 32;
    const int chunk = sc ? bx - 32 : bx;
    const int N = sc ? 1024 : 4096;
    const float invN = sc ? (1.0f / 1024.0f) : (1.0f / 4096.0f);
    const int nch = sc ? 8 : 32;
    const int n0 = chunk * 128;
    const short* Eb = (sc ? Eg1 : Eg0) + (long)b * 65 * N;
    const float* pin = sc ? pin1 : pin0;
    const int nin = sc ? nin1 : nin0;
    const float* fb = (sc ? feat1 : feat0) + (long)b * 128 * N;
    float* part = sc ? part1 : part0;
    if (t < 65) {
        float s = 0.f;
        for (int ch = 0; ch < nin; ch++) s += pin[((long)b * nin + ch) * 65 + t];
        eus[t] = (1.0f / 65.0f) / s;
    }
    for (int it = t; it < 1040; it += 256) {
        int k = it >> 4, n8 = it & 15;
        *(short8*)(Es + k * 136 + n8 * 8) = *(const short8*)(Eb + (long)k * N + n0 + n8 * 8);
    }
    __syncthreads();
    if (t < 128) {
        float sv = 0.f;
        #pragma unroll 5
        for (int k = 0; k < 65; k++) sv += bf2f(Es[k * 136 + t]) * eus[k];
        evs[t] = invN / sv;
    }
    __syncthreads();
    // P in-place (rows 0..63)
    for (int it = t; it < 8192; it += 256) {
        int k = it >> 7, n = it & 127;
        Es[k * 136 + n] = f2bf(bf2f(Es[k * 136 + n]) * eus[k] * evs[n]);
    }
    __syncthreads();
    const int wid = t >> 6, lane = t & 63;
    float* pb = part + ((long)b * nch + chunk) * 8256;
    for (int k = wid; k < 64; k += 4) {
        const short* er = Es + k * 136 + lane * 2;
        float s = bf2f(er[0]) + bf2f(er[1]);
        #pragma unroll
        for (int off = 32; off >= 1; off >>= 1) s += __shfl_xor(s, off);
        if (lane == 0) pb[8192 + k] = s;
    }
    const int cq = t & 31, kq = t >> 5;
    float a[4][8];
    #pragma unroll
    for (int i = 0; i < 4; i++)
        #pragma unroll
        for (int j = 0; j < 8; j++) a[i][j] = 0.f;
    for (int ns = 0; ns < 128; ns += 32) {
        __syncthreads();
        {
            int np = t & 31, cg = t >> 5;
            #pragma unroll
            for (int ii = 0; ii < 16; ii++) {
                int c = cg * 16 + ii;
                fs[c * 33 + np] = fb[(long)c * N + n0 + ns + np];
            }
        }
        __syncthreads();
        for (int np = 0; np < 32; np++) {
            float pv[8];
            #pragma unroll
            for (int j = 0; j < 8; j++) pv[j] = bf2f(Es[(8 * kq + j) * 136 + ns + np]);
            #pragma unroll
            for (int i = 0; i < 4; i++) {
                float fv = fs[(cq + 32 * i) * 33 + np];
                #pragma unroll
                for (int j = 0; j < 8; j++) a[i][j] += fv * pv[j];
            }
        }
    }
    #pragma unroll
    for (int i = 0; i < 4; i++)
        #pragma unroll
        for (int j = 0; j < 8; j++)
            pb[(cq + 32 * i) * 64 + 8 * kq + j] = a[i][j];
}

// ---------------- reduce_final: per-batch chunk-reduce both scales + normalize + output ----------------
__global__ __launch_bounds__(256) void reduce_final(
    const float* __restrict__ part0, const float* __restrict__ part1,
    float* __restrict__ out, int b0)
{
    __shared__ float cn[4][32];
    __shared__ float red[4];
    const int b = blockIdx.x;
    const int t = threadIdx.x;
    const int c = t & 127, kh = t >> 7;     // thread owns (c, k = kh*32+j)
    const int wid = t >> 6, lane = t & 63;
    float g[32];
    #pragma unroll
    for (int j = 0; j < 32; j++) g[j] = 0.f;
    for (int s = 0; s < 2; s++) {
        const int nch = s ? 8 : 32;
        const float* pb = (s ? part1 : part0) + (long)b * nch * 8256;
        float a[32], rs[32];
        #pragma unroll
        for (int j = 0; j < 32; j++) { a[j] = 0.f; rs[j] = 0.f; }
        for (int ch = 0; ch < nch; ch++) {
            const float* p = pb + (long)ch * 8256;
            #pragma unroll
            for (int j = 0; j < 32; j++) a[j] += p[c * 64 + kh * 32 + j];
            #pragma unroll
            for (int j = 0; j < 32; j++) rs[j] += p[8192 + kh * 32 + j];
        }
        float s2[32];
        #pragma unroll
        for (int j = 0; j < 32; j++) {
            a[j] *= 1.0f / (rs[j] + 1e-8f);
            s2[j] = a[j] * a[j];
        }
        #pragma unroll
        for (int off = 32; off >= 1; off >>= 1)
            #pragma unroll
            for (int j = 0; j < 32; j++) s2[j] += __shfl_xor(s2[j], off);
        if (lane == 0) {
            #pragma unroll
            for (int j = 0; j < 32; j++) cn[wid][j] = s2[j];
        }
        __syncthreads();
        #pragma unroll
        for (int j = 0; j < 32; j++) {
            float tot = cn[kh * 2][j] + cn[kh * 2 + 1][j];
            float inv = 1.0f / fmaxf(sqrtf(tot), 1e-12f);
            g[j] += a[j] * inv;
        }
        __syncthreads();    // cn reuse
    }
    float ss = 0.f;
    #pragma unroll
    for (int j = 0; j < 32; j++) { g[j] *= 0.5f; ss += g[j] * g[j]; }
    #pragma unroll
    for (int off = 32; off >= 1; off >>= 1) ss += __shfl_xor(ss, off);
    if (lane == 0) red[wid] = ss;
    __syncthreads();
    float tot = red[0] + red[1] + red[2] + red[3];
    float inv = 1.0f / fmaxf(sqrtf(tot), 1e-12f);
    float* o = out + (long)(b0 + b) * 8192 + c * 64 + kh * 32;
    #pragma unroll
    for (int j = 0; j < 32; j++) o[j] = g[j] * inv;
}

extern "C" void kernel_launch(void* const* d_in, const int* in_sizes, int n_in,
                              void* d_out, int out_size, void* d_ws, size_t ws_size,
                              hipStream_t stream)
{
    (void)in_sizes; (void)n_in; (void)out_size;
    const float* x = (const float*)d_in[0];
    WSet ws2[2];
    const float* fb2p[2];
    for (int s = 0; s < 2; s++) {
        int o = 1 + s * 12;
        ws2[s].fw1 = (const float*)d_in[o + 0];  ws2[s].fb1 = (const float*)d_in[o + 1];
        ws2[s].fw2 = (const float*)d_in[o + 2];  fb2p[s]    = (const float*)d_in[o + 3];
        ws2[s].sw1 = (const float*)d_in[o + 4];  ws2[s].sb1 = (const float*)d_in[o + 5];
        ws2[s].sw2 = (const float*)d_in[o + 6];  ws2[s].sb2 = (const float*)d_in[o + 7];
        ws2[s].dw1 = (const float*)d_in[o + 8];  ws2[s].db1 = (const float*)d_in[o + 9];
        ws2[s].dw2 = (const float*)d_in[o + 10]; ws2[s].db2 = (const float*)d_in[o + 11];
    }

    const size_t fixed = ((size_t)2*491520*2 + 2*65536*2 + 2*98304*2
                        + 2*1280*4 + 2*128*4) + (1 << 16);
    const size_t perb = (size_t)128*4096*4 + (size_t)128*1024*4
                      + (size_t)65*4096*2 + (size_t)65*1024*2
                      + (size_t)(64+32)*65*4 + (size_t)(16+8)*65*4
                      + (size_t)32*8256*4 + (size_t)8*8256*4 + 8192;
    int CB = 4;
    const int cand[3] = {16, 8, 4};
    for (int ci = 0; ci < 3; ci++)
        if (fixed + (size_t)cand[ci] * perb <= ws_size) { CB = cand[ci]; break; }

    char* p = (char*)d_ws;
    auto alloc = [&](size_t bytes) -> char* {
        char* r = p; p += (bytes + 255) & ~(size_t)255; return r;
    };
    short* W1f   = (short*)alloc((size_t)2 * 491520 * 2);
    short* W2af  = (short*)alloc((size_t)2 * 65536 * 2);
    short* W2bf  = (short*)alloc((size_t)2 * 98304 * 2);
    float* B1p   = (float*)alloc((size_t)2 * 1280 * 4);
    float* B2bp  = (float*)alloc((size_t)2 * 128 * 4);
    float* feat0 = (float*)alloc((size_t)CB * 128 * 4096 * 4);
    float* feat1 = (float*)alloc((size_t)CB * 128 * 1024 * 4);
    short* Eg0   = (short*)alloc((size_t)CB * 65 * 4096 * 2);
    short* Eg1   = (short*)alloc((size_t)CB * 65 * 1024 * 2);
    float* puA0  = (float*)alloc((size_t)CB * 64 * 65 * 4);
    float* puA1  = (float*)alloc((size_t)CB * 16 * 65 * 4);
    float* puB0  = (float*)alloc((size_t)CB * 32 * 65 * 4);
    float* puB1  = (float*)alloc((size_t)CB * 8 * 65 * 4);
    float* part0 = (float*)alloc((size_t)CB * 32 * 8256 * 4);
    float* part1 = (float*)alloc((size_t)CB * 8 * 8256 * 4);

    wprep<<<dim3(2566, 2), 256, 0, stream>>>(ws2[0], ws2[1], W1f, W2af, W2bf, B1p, B2bp);

    for (int b0 = 0; b0 < 16; b0 += CB) {
        fused_mlp<<<dim3(80, CB), 256, 0, stream>>>(
            W1f, B1p, W2af, fb2p[0], fb2p[1], W2bf, B2bp,
            x + (size_t)b0 * 384 * 4096, feat0, feat1, Eg0, Eg1, puA0, puA1);
        sk_step<<<dim3(40, CB), 128, 0, stream>>>(Eg0, Eg1, puA0, puA1, puB0, puB1, 64, 16);
        sk_step<<<dim3(40, CB), 128, 0, stream>>>(Eg0, Eg1, puB0, puB1, puA0, puA1, 32, 8);
        sk_desc<<<dim3(40, CB), 256, 0, stream>>>(Eg0, Eg1, puA0, puA1,
                                                  feat0, feat1, part0, part1, 32, 8);
        reduce_final<<<CB, 256, 0, stream>>>(part0, part1, (float*)d_out, b0);
    }
}